// Round 13
// baseline (352.457 us; speedup 1.0000x reference)
//
#include <hip/hip_runtime.h>
#include <cmath>

#define NSP 1728   // 12*12*12
#define BB  2      // batch
#define SS  12
#define SREP 512   // stats replica stride (BB*128*2)

typedef __attribute__((ext_vector_type(8))) short short8;
typedef __attribute__((ext_vector_type(4))) short short4v;
typedef __attribute__((ext_vector_type(4))) float floatx4;

__device__ __forceinline__ short f2bf(float f) {
    unsigned u = __float_as_uint(f);
    u += 0x7fff + ((u >> 16) & 1);
    return (short)(u >> 16);
}
__device__ __forceinline__ unsigned pack2bf(float a, float b) {
    unsigned ua = __float_as_uint(a); ua += 0x7fff + ((ua >> 16) & 1);
    unsigned ub = __float_as_uint(b); ub += 0x7fff + ((ub >> 16) & 1);
    return (ua >> 16) | (ub & 0xffff0000u);
}
__device__ __forceinline__ short8 ld8(const short* p) {
    short4v a = *(const short4v*)p;
    short4v b = *(const short4v*)(p + 4);
    return __builtin_shufflevector(a, b, 0, 1, 2, 3, 4, 5, 6, 7);
}
// raw hardware exp2 (1 inst; inputs here are O(±3), far from edge cases)
__device__ __forceinline__ float fexp2(float x) {
    float r;
    asm("v_exp_f32 %0, %1" : "=v"(r) : "v"(x));
    return r;
}

// ---------------- block-wide dual reduction (sum, sumsq) -------------------
__device__ __forceinline__ void block_reduce2(float& s, float& s2) {
    __shared__ float red[8][2];
    __syncthreads();
    #pragma unroll
    for (int o = 32; o; o >>= 1) {
        s  += __shfl_down(s,  o, 64);
        s2 += __shfl_down(s2, o, 64);
    }
    int lane = threadIdx.x & 63, w = threadIdx.x >> 6;
    if (lane == 0) { red[w][0] = s; red[w][1] = s2; }
    __syncthreads();
    int nw = (blockDim.x + 63) >> 6;
    if (threadIdx.x == 0) {
        float a = 0.f, b = 0.f;
        for (int i = 0; i < nw; i++) { a += red[i][0]; b += red[i][1]; }
        red[0][0] = a; red[0][1] = b;
    }
    __syncthreads();
    s = red[0][0]; s2 = red[0][1];
}

// ======= weight prep: fp32 -> bf16, all 8 conv weight matrices =============
#define WTOT 376832
__global__ __launch_bounds__(256) void prep_kernel(
        const float* __restrict__ s0, const float* __restrict__ s1,
        const float* __restrict__ s2, const float* __restrict__ s3,
        const float* __restrict__ s4, const float* __restrict__ s5,
        const float* __restrict__ s6, const float* __restrict__ s7,
        short* __restrict__ dst) {
    const int offs[9] = {0, 16384, 49152, 114688, 180224, 229376, 245760, 311296, WTOT};
    const float* srcs[8] = {s0, s1, s2, s3, s4, s5, s6, s7};
    int e = blockIdx.x * 1024 + threadIdx.x * 4;
    #pragma unroll
    for (int k = 0; k < 4; k++) {
        int idx = e + k;
        if (idx >= WTOT) return;
        int seg = 0;
        while (idx >= offs[seg + 1]) seg++;
        dst[idx] = f2bf(srcs[seg][idx - offs[seg]]);
    }
}

// ======= MFMA 1x1 conv =====================================================
// C^T[n][co] = X'^T[n][ci] x W[co][ci]:  M = n (16/block), N = co, K = ci.
// grid (BB*108 n-tiles, COUT/64 co-tiles); 4 waves, each owns 16 cos.
// Stats are 8-way replicated (writer replica = n-tile&7; fold preamble sums
// nrep replicas) to cut atomic serialization.
template<int CIN, int COUT>
__global__ __launch_bounds__(256) void convm_kernel(
        const float* __restrict__ in, const short* __restrict__ wb,
        const float* __restrict__ biasc,
        const float* __restrict__ se_s,
        const float* __restrict__ sw1, const float* __restrict__ sb1,
        const float* __restrict__ sw2, const float* __restrict__ sb2, int seR,
        const float* __restrict__ fstats, const float* __restrict__ fg,
        const float* __restrict__ fb, int fgs, int nrep,
        const float* __restrict__ po, const float* __restrict__ pl,
        float* __restrict__ xout,
        const float* resid, float* out, float* stats_out, int act) {
    constexpr int XP = CIN + 8;          // bf16 row pitch (16B-multiple rows)
    __shared__ float sc[CIN];
    __shared__ float sh[CIN];
    __shared__ float hid[128];
    __shared__ __align__(16) short xa[16 * XP];
    int flat = blockIdx.x;
    int b = flat / 108, mt = flat % 108;
    int n0 = mt * 16;
    int tid = threadIdx.x;

    if (po) {
        // ---- attention-merge staging: X = (sum_js po) / l, ci = h*16+d ----
        if (tid < 128) {
            int hh = tid >> 4, j = tid & 15;
            float l = 0.f;
            #pragma unroll
            for (int js = 0; js < 6; js++)
                l += pl[(size_t)((b * 8 + hh) * 6 + js) * NSP + n0 + j];
            hid[tid] = 1.f / l;
        }
        __syncthreads();
        #pragma unroll
        for (int i = 0; i < CIN / 64; i++) {
            int e = tid + i * 256;
            int ci = e >> 2;
            int jj = (e & 3) * 4;
            int hh = ci >> 4, d = ci & 15;
            float4 acc = {0.f, 0.f, 0.f, 0.f};
            #pragma unroll
            for (int js = 0; js < 6; js++) {
                float4 pv = *(const float4*)(po +
                    ((size_t)((b * 8 + hh) * 6 + js) * 16 + d) * NSP + n0 + jj);
                acc.x += pv.x; acc.y += pv.y; acc.z += pv.z; acc.w += pv.w;
            }
            float4 li = *(const float4*)(hid + hh * 16 + jj);
            xa[(jj + 0) * XP + ci] = f2bf(acc.x * li.x);
            xa[(jj + 1) * XP + ci] = f2bf(acc.y * li.y);
            xa[(jj + 2) * XP + ci] = f2bf(acc.z * li.z);
            xa[(jj + 3) * XP + ci] = f2bf(acc.w * li.w);
        }
        __syncthreads();
    } else {
    // ---- preamble: per-ci scale/shift ----
    if (sw1) {
        for (int c = tid; c < CIN; c += 256) { sc[c] = se_s[b * CIN + c]; sh[c] = 0.f; }
        __syncthreads();
        for (int r = tid; r < seR; r += 256) {
            const float* wr = sw1 + (size_t)r * CIN;
            float h0 = sb1[r], h1 = 0.f, h2 = 0.f, h3 = 0.f;
            for (int c = 0; c < CIN; c += 4) {
                h0 = fmaf(wr[c],     sc[c],     h0);
                h1 = fmaf(wr[c + 1], sc[c + 1], h1);
                h2 = fmaf(wr[c + 2], sc[c + 2], h2);
                h3 = fmaf(wr[c + 3], sc[c + 3], h3);
            }
            float hv = (h0 + h1) + (h2 + h3);
            hid[r] = hv / (1.f + __expf(-hv));
        }
        __syncthreads();
        for (int ci = tid; ci < CIN; ci += 256) {
            const float* wr = sw2 + (size_t)ci * seR;
            float g0 = sb2[ci], g1 = 0.f, g2 = 0.f, g3 = 0.f;
            for (int r = 0; r < seR; r += 4) {
                g0 = fmaf(wr[r],     hid[r],     g0);
                g1 = fmaf(wr[r + 1], hid[r + 1], g1);
                g2 = fmaf(wr[r + 2], hid[r + 2], g2);
                g3 = fmaf(wr[r + 3], hid[r + 3], g3);
            }
            float gv = (g0 + g1) + (g2 + g3);
            sc[ci] = 1.f / (1.f + __expf(-gv));
        }
    } else if (fstats) {
        for (int c = tid; c < CIN; c += 256) {
            int g0 = c / fgs;
            float S = 0.f, S2 = 0.f;
            for (int k = 0; k < fgs; k++) {
                int base = (b * CIN + g0 * fgs + k) * 2;
                for (int r = 0; r < nrep; r++) {
                    S  += fstats[r * SREP + base];
                    S2 += fstats[r * SREP + base + 1];
                }
            }
            float N = fgs * (float)NSP;
            float mean = S / N, var = S2 / N - mean * mean;
            float s = rsqrtf(var + 1e-5f) * fg[c];
            sc[c] = s;
            sh[c] = fb[c] - mean * s;
        }
    } else {
        for (int c = tid; c < CIN; c += 256) { sc[c] = 1.f; sh[c] = 0.f; }
    }
    __syncthreads();

    // ---- stage X' tile [n=16][ci] bf16 (fp32 fold applied pre-round) ----
    bool dosw = (xout != nullptr) && (blockIdx.y == 0);
    #pragma unroll
    for (int i = 0; i < CIN / 64; i++) {
        int e = tid + i * 256;           // e in [0, 4*CIN)
        int ci = e >> 2;
        int jj = (e & 3) * 4;
        size_t gi = ((size_t)b * CIN + ci) * NSP + n0 + jj;
        float4 v4 = *(const float4*)(in + gi);
        float s_ = sc[ci], h_ = sh[ci];
        float v0 = fmaf(v4.x, s_, h_), v1 = fmaf(v4.y, s_, h_);
        float v2 = fmaf(v4.z, s_, h_), v3 = fmaf(v4.w, s_, h_);
        if (dosw) {
            float4 o; o.x = v0; o.y = v1; o.z = v2; o.w = v3;
            *(float4*)(xout + gi) = o;
        }
        xa[(jj + 0) * XP + ci] = f2bf(v0);
        xa[(jj + 1) * XP + ci] = f2bf(v1);
        xa[(jj + 2) * XP + ci] = f2bf(v2);
        xa[(jj + 3) * XP + ci] = f2bf(v3);
    }
    __syncthreads();
    }

    // ---- compute: no further barriers; dual acc chains for MFMA ILP ----
    int lane = tid & 63, wv = tid >> 6;
    int col = lane & 15, quad = lane >> 4;
    short8 afr[CIN / 32];
    #pragma unroll
    for (int kc = 0; kc < CIN / 32; kc++)
        afr[kc] = ld8(xa + col * XP + kc * 32 + quad * 8);

    int cobase = blockIdx.y * 64 + wv * 16;
    int co = cobase + col;
    const short* wrow = wb + (size_t)co * CIN;
    floatx4 acc0 = {0.f, 0.f, 0.f, 0.f}, acc1 = {0.f, 0.f, 0.f, 0.f};
    #pragma unroll
    for (int kc = 0; kc < CIN / 32; kc += 2) {
        short8 bw0 = ld8(wrow + kc * 32 + quad * 8);
        short8 bw1 = ld8(wrow + (kc + 1) * 32 + quad * 8);
        acc0 = __builtin_amdgcn_mfma_f32_16x16x32_bf16(afr[kc],     bw0, acc0, 0, 0, 0);
        acc1 = __builtin_amdgcn_mfma_f32_16x16x32_bf16(afr[kc + 1], bw1, acc1, 0, 0, 0);
    }
    float bv = biasc ? biasc[co] : 0.f;
    float r0 = acc0[0] + acc1[0] + bv, r1 = acc0[1] + acc1[1] + bv;
    float r2 = acc0[2] + acc1[2] + bv, r3 = acc0[3] + acc1[3] + bv;
    if (act == 2) {
        r0 = 0.5f * r0 * (1.f + erff(r0 * 0.70710678118654752f));
        r1 = 0.5f * r1 * (1.f + erff(r1 * 0.70710678118654752f));
        r2 = 0.5f * r2 * (1.f + erff(r2 * 0.70710678118654752f));
        r3 = 0.5f * r3 * (1.f + erff(r3 * 0.70710678118654752f));
    }
    size_t oi = ((size_t)b * COUT + co) * NSP + n0 + quad * 4;
    if (resid) {
        float4 rv = *(const float4*)(resid + oi);
        r0 += rv.x; r1 += rv.y; r2 += rv.z; r3 += rv.w;
    }
    float4 ov; ov.x = r0; ov.y = r1; ov.z = r2; ov.w = r3;
    *(float4*)(out + oi) = ov;
    if (stats_out) {
        float s  = (r0 + r1) + (r2 + r3);
        float s2 = (r0 * r0 + r1 * r1) + (r2 * r2 + r3 * r3);
        s  += __shfl_xor(s,  16, 64);
        s  += __shfl_xor(s,  32, 64);
        s2 += __shfl_xor(s2, 16, 64);
        s2 += __shfl_xor(s2, 32, 64);
        if (lane < 16) {
            float* so = stats_out + (mt & 7) * SREP;
            atomicAdd(&so[(b * COUT + cobase + lane) * 2],     s);
            atomicAdd(&so[(b * COUT + cobase + lane) * 2 + 1], s2);
        }
    }
}

// ======= post: out = IN(p0) + resid, emits raw stats of out ================
__global__ __launch_bounds__(256) void post_kernel(
        const float* __restrict__ p0,
        const float* __restrict__ ng, const float* __restrict__ nb,
        const float* resid, float* out, float* __restrict__ stats_out, int C) {
    int bc = blockIdx.x;
    int c  = bc % C;
    const float* a = p0 + (size_t)bc * NSP;
    float r[7];
    float s = 0.f, s2 = 0.f;
    #pragma unroll
    for (int i = 0; i < 7; i++) {
        int n = threadIdx.x + i * 256;
        if (n < NSP) { r[i] = a[n]; s += r[i]; s2 += r[i] * r[i]; }
        else r[i] = 0.f;
    }
    block_reduce2(s, s2);
    float mean = s / NSP;
    float var = s2 / NSP - mean * mean;
    float rstd = rsqrtf(var + 1e-5f);
    float gc = ng[c], bc2 = nb[c];
    float os = 0.f, os2 = 0.f;
    #pragma unroll
    for (int i = 0; i < 7; i++) {
        int n = threadIdx.x + i * 256;
        if (n < NSP) {
            float v = (r[i] - mean) * rstd * gc + bc2;
            size_t oi = (size_t)bc * NSP + n;
            if (resid) v += resid[oi];
            out[oi] = v;
            os += v; os2 += v * v;
        }
    }
    if (stats_out) {
        block_reduce2(os, os2);
        if (threadIdx.x == 0) {
            stats_out[bc * 2]     = os;
            stats_out[bc * 2 + 1] = os2;
        }
    }
}

// ======= IN+SiLU + depthwise 3x3x3 (halo LDS) + IN+SiLU + SE-squeeze =======
__global__ __launch_bounds__(256) void indw_kernel(
        const float* __restrict__ in,
        const float* __restrict__ g1, const float* __restrict__ b1,
        const float* __restrict__ dw,
        const float* __restrict__ g2, const float* __restrict__ b2,
        float* __restrict__ out, float* __restrict__ se_s, int C) {
    int bc = blockIdx.x;
    int c  = bc % C;
    __shared__ float tile[14 * 14 * 14];   // zero-padded halo volume
    __shared__ float wsh[27];
    const float* ip = in + (size_t)bc * NSP;
    float r[7];
    float s = 0.f, s2 = 0.f;
    for (int i = threadIdx.x; i < 2744; i += 256) tile[i] = 0.f;
    #pragma unroll
    for (int i = 0; i < 7; i++) {
        int n = threadIdx.x + i * 256;
        if (n < NSP) { r[i] = ip[n]; s += r[i]; s2 += r[i] * r[i]; }
        else r[i] = 0.f;
    }
    if (threadIdx.x < 27) wsh[threadIdx.x] = dw[(size_t)c * 27 + threadIdx.x];
    block_reduce2(s, s2);
    float mean = s / NSP, var = s2 / NSP - (s / NSP) * (s / NSP);
    float rstd = rsqrtf(var + 1e-5f);
    float gc = g1[c], bc1 = b1[c];
    #pragma unroll
    for (int i = 0; i < 7; i++) {
        int n = threadIdx.x + i * 256;
        if (n < NSP) {
            int z = n / 144, y = (n / 12) % 12, x = n % 12;
            float v = (r[i] - mean) * rstd * gc + bc1;
            tile[((z + 1) * 14 + y + 1) * 14 + x + 1] = v / (1.f + __expf(-v));
        }
    }
    __syncthreads();
    float d[7];
    #pragma unroll
    for (int i = 0; i < 7; i++) {
        int n = threadIdx.x + i * 256;
        d[i] = 0.f;
        if (n < NSP) {
            int z = n / 144, y = (n / 12) % 12, x = n % 12;
            const float* ctr = tile + ((z + 1) * 14 + y + 1) * 14 + x + 1;
            float acc = 0.f;
            #pragma unroll
            for (int dz = 0; dz < 3; dz++)
                #pragma unroll
                for (int dy = 0; dy < 3; dy++)
                    #pragma unroll
                    for (int dx = 0; dx < 3; dx++)
                        acc = fmaf(wsh[dz * 9 + dy * 3 + dx],
                                   ctr[(dz - 1) * 196 + (dy - 1) * 14 + (dx - 1)], acc);
            d[i] = acc;
        }
    }
    s = 0.f; s2 = 0.f;
    #pragma unroll
    for (int i = 0; i < 7; i++) {
        int n = threadIdx.x + i * 256;
        if (n < NSP) { s += d[i]; s2 += d[i] * d[i]; }
    }
    block_reduce2(s, s2);
    mean = s / NSP; var = s2 / NSP - mean * mean;
    rstd = rsqrtf(var + 1e-5f);
    float gc2 = g2[c], bc2 = b2[c];
    float ssum = 0.f;
    float* op = out + (size_t)bc * NSP;
    #pragma unroll
    for (int i = 0; i < 7; i++) {
        int n = threadIdx.x + i * 256;
        if (n < NSP) {
            float v = (d[i] - mean) * rstd * gc2 + bc2;
            v = v / (1.f + __expf(-v));
            op[n] = v;
            ssum += v;
        }
    }
    float dummy = 0.f;
    block_reduce2(ssum, dummy);
    if (threadIdx.x == 0) se_s[bc] = ssum / NSP;
}

// ======= MFMA flash attention, j-split 6, S^T formulation ==================
#define AKT 20
#define AVT 296
#define APT 36
#define JCH 288
__global__ __launch_bounds__(256) void attn_split_kernel(const float* __restrict__ qkv,
                                                         float* __restrict__ po,
                                                         float* __restrict__ pl) {
    __shared__ __align__(16) short kt[JCH * AKT];   // [j][d]
    __shared__ __align__(16) short vt[16 * AVT];    // [d][j]
    __shared__ __align__(16) short pt[4][16 * APT]; // per wave [q][j]
    int bh = blockIdx.x;
    int b = bh >> 3, h = bh & 7;
    int js = blockIdx.z;
    int j0 = js * JCH;
    const float* base = qkv + (size_t)b * 384 * NSP;
    const float* qp = base + (size_t)(h * 16) * NSP;
    const float* kp = base + (size_t)(128 + h * 16) * NSP;
    const float* vp = base + (size_t)(256 + h * 16) * NSP;
    for (int t = threadIdx.x; t < 16 * 144; t += 256) {
        int d = t / 144, j = (t - d * 144) * 2;
        float2 kv2 = *(const float2*)(kp + (size_t)d * NSP + j0 + j);
        float2 vv2 = *(const float2*)(vp + (size_t)d * NSP + j0 + j);
        kt[j * AKT + d]       = f2bf(kv2.x);
        kt[(j + 1) * AKT + d] = f2bf(kv2.y);
        *(unsigned*)(vt + d * AVT + j) = pack2bf(vv2.x, vv2.y);
    }
    int wave = threadIdx.x >> 6, lane = threadIdx.x & 63;
    int m = lane & 15, quad = lane >> 4;
    int q0 = (blockIdx.y * 4 + wave) * 16;
    short* ptw = pt[wave];
    short8 qa;
    #pragma unroll
    for (int i = 0; i < 8; i++) qa[i] = 0;
    if (quad < 2) {
        #pragma unroll
        for (int i = 0; i < 8; i++) {
            int d = quad * 8 + i;
            qa[i] = f2bf(qp[(size_t)d * NSP + q0 + m] * 0.36067376022224085f);
        }
    }
    __syncthreads();
    floatx4 o = {0.f, 0.f, 0.f, 0.f};
    float ls = 0.f;
    for (int s = 0; s < 9; s++) {
        int jl = s * 32;
        short8 ak0, ak1;
        #pragma unroll
        for (int i = 0; i < 8; i++) { ak0[i] = 0; ak1[i] = 0; }
        if (quad < 2) {
            ak0 = ld8(kt + (jl + m) * AKT + quad * 8);
            ak1 = ld8(kt + (jl + 16 + m) * AKT + quad * 8);
        }
        floatx4 s0 = {0.f, 0.f, 0.f, 0.f}, s1 = {0.f, 0.f, 0.f, 0.f};
        s0 = __builtin_amdgcn_mfma_f32_16x16x32_bf16(ak0, qa, s0, 0, 0, 0);
        s1 = __builtin_amdgcn_mfma_f32_16x16x32_bf16(ak1, qa, s1, 0, 0, 0);
        float p0r0 = fexp2(s0[0]), p0r1 = fexp2(s0[1]), p0r2 = fexp2(s0[2]), p0r3 = fexp2(s0[3]);
        float p1r0 = fexp2(s1[0]), p1r1 = fexp2(s1[1]), p1r2 = fexp2(s1[2]), p1r3 = fexp2(s1[3]);
        ls += (p0r0 + p0r1) + (p0r2 + p0r3) + (p1r0 + p1r1) + (p1r2 + p1r3);
        uint2 w0, w1;
        w0.x = pack2bf(p0r0, p0r1); w0.y = pack2bf(p0r2, p0r3);
        w1.x = pack2bf(p1r0, p1r1); w1.y = pack2bf(p1r2, p1r3);
        *(uint2*)(ptw + m * APT + quad * 4)      = w0;
        *(uint2*)(ptw + m * APT + 16 + quad * 4) = w1;
        short8 av = ld8(vt + m * AVT + jl + quad * 8);
        short8 pb = ld8(ptw + m * APT + quad * 8);
        o = __builtin_amdgcn_mfma_f32_16x16x32_bf16(av, pb, o, 0, 0, 0);
    }
    ls += __shfl_xor(ls, 16, 64);
    ls += __shfl_xor(ls, 32, 64);
    size_t pbase = ((size_t)(bh * 6 + js) * 16) * NSP;
    #pragma unroll
    for (int r = 0; r < 4; r++)
        po[pbase + (size_t)(quad * 4 + r) * NSP + q0 + m] = o[r];
    if (quad == 0) pl[(size_t)(bh * 6 + js) * NSP + q0 + m] = ls;
}

// ======= shuffle attn final: inline gates + gnstats + gating + shuffle =====
// st has 8 replicas (stride SREP); sum them.
__global__ void sfinal_kernel(const float* __restrict__ X,
                              const float* __restrict__ st,
                              const float* __restrict__ cw1,
                              const float* __restrict__ cw2,
                              const float* __restrict__ gng,
                              const float* __restrict__ gnb,
                              const float* __restrict__ sw,
                              float* __restrict__ out) {
    int bg = blockIdx.x;
    int b = bg >> 2, g = bg & 3;
    __shared__ float swl[256];
    for (int i = threadIdx.x; i < 256; i += 64) swl[i] = sw[i];
    __syncthreads();
    float pooled[16];
    #pragma unroll
    for (int j = 0; j < 16; j++) {
        float S = 0.f;
        #pragma unroll
        for (int r = 0; r < 8; r++)
            S += st[r * SREP + (b * 128 + g * 32 + j) * 2];
        pooled[j] = S * (1.f / NSP);
    }
    float hid[4];
    #pragma unroll
    for (int r = 0; r < 4; r++) {
        float a = 0.f;
        #pragma unroll
        for (int j = 0; j < 16; j++) a = fmaf(cw1[r * 16 + j], pooled[j], a);
        hid[r] = a / (1.f + __expf(-a));
    }
    float gate[16];
    #pragma unroll
    for (int j = 0; j < 16; j++) {
        float a = 0.f;
        #pragma unroll
        for (int r = 0; r < 4; r++) a = fmaf(cw2[j * 4 + r], hid[r], a);
        gate[j] = 1.f / (1.f + __expf(-a));
    }
    float gmean[2], grstd[2];
    #pragma unroll
    for (int t = 0; t < 2; t++) {
        float S = 0.f, S2 = 0.f;
        #pragma unroll
        for (int k = 0; k < 8; k++) {
            int c = g * 32 + 16 + t * 8 + k;
            #pragma unroll
            for (int r = 0; r < 8; r++) {
                S  += st[r * SREP + (b * 128 + c) * 2];
                S2 += st[r * SREP + (b * 128 + c) * 2 + 1];
            }
        }
        float N = 8.f * NSP;
        gmean[t] = S / N;
        grstd[t] = rsqrtf(S2 / N - gmean[t] * gmean[t] + 1e-5f);
    }
    int n = blockIdx.y * 64 + threadIdx.x;
    const float* xb = X + (size_t)b * 128 * NSP;
    #pragma unroll
    for (int j = 0; j < 16; j++) {
        float v = xb[(size_t)(g * 32 + j) * NSP + n] * gate[j];
        int k = g * 16 + j;
        int cp = (k % 32) * 4 + (k / 32);
        out[((size_t)b * 128 + cp) * NSP + n] = v;
    }
    float sgn[16];
    #pragma unroll
    for (int j = 0; j < 16; j++) {
        int grp = j >> 3;
        float xv = xb[(size_t)(g * 32 + 16 + j) * NSP + n];
        sgn[j] = (xv - gmean[grp]) * grstd[grp] * gng[j] + gnb[j];
    }
    #pragma unroll
    for (int j = 0; j < 16; j++) {
        float a = 0.f;
        #pragma unroll
        for (int jp = 0; jp < 16; jp++) a = fmaf(swl[j * 16 + jp], sgn[jp], a);
        float v = (1.f / (1.f + __expf(-a))) * xb[(size_t)(g * 32 + 16 + j) * NSP + n];
        int k = 64 + g * 16 + j;
        int cp = (k % 32) * 4 + (k / 32);
        out[((size_t)b * 128 + cp) * NSP + n] = v;
    }
}

// ===========================================================================
extern "C" void kernel_launch(void* const* d_in, const int* in_sizes, int n_in,
                              void* d_out, int out_size, void* d_ws, size_t ws_size,
                              hipStream_t stream) {
    const float* x     = (const float*)d_in[0];
    const float* m1_ew = (const float*)d_in[1];
    const float* m1_g1 = (const float*)d_in[2];
    const float* m1_b1 = (const float*)d_in[3];
    const float* m1_dw = (const float*)d_in[4];
    const float* m1_g2 = (const float*)d_in[5];
    const float* m1_b2 = (const float*)d_in[6];
    const float* m1_sw1= (const float*)d_in[7];
    const float* m1_sb1= (const float*)d_in[8];
    const float* m1_sw2= (const float*)d_in[9];
    const float* m1_sb2= (const float*)d_in[10];
    const float* m1_pw = (const float*)d_in[11];
    const float* m1_g3 = (const float*)d_in[12];
    const float* m1_b3 = (const float*)d_in[13];
    const float* m2_ew = (const float*)d_in[14];
    const float* m2_g1 = (const float*)d_in[15];
    const float* m2_b1 = (const float*)d_in[16];
    const float* m2_dw = (const float*)d_in[17];
    const float* m2_g2 = (const float*)d_in[18];
    const float* m2_b2 = (const float*)d_in[19];
    const float* m2_sw1= (const float*)d_in[20];
    const float* m2_sb1= (const float*)d_in[21];
    const float* m2_sw2= (const float*)d_in[22];
    const float* m2_sb2= (const float*)d_in[23];
    const float* m2_pw = (const float*)d_in[24];
    const float* m2_g3 = (const float*)d_in[25];
    const float* m2_b3 = (const float*)d_in[26];
    const float* t_n1g = (const float*)d_in[27];
    const float* t_n1b = (const float*)d_in[28];
    const float* t_qkv = (const float*)d_in[29];
    const float* t_pw  = (const float*)d_in[30];
    const float* t_pb  = (const float*)d_in[31];
    const float* t_n2g = (const float*)d_in[32];
    const float* t_n2b = (const float*)d_in[33];
    const float* t_mw1 = (const float*)d_in[34];
    const float* t_mb1 = (const float*)d_in[35];
    const float* t_mw2 = (const float*)d_in[36];
    const float* t_mb2 = (const float*)d_in[37];
    const float* s_cw1 = (const float*)d_in[38];
    const float* s_cw2 = (const float*)d_in[39];
    const float* s_gng = (const float*)d_in[40];
    const float* s_gnb = (const float*)d_in[41];
    const float* s_sw  = (const float*)d_in[42];

    float* out = (float*)d_out;

    float* ws = (float*)d_ws;
    float* bufA   = ws;                                 // 2*512*NSP (also attn po)
    float* bufB   = bufA + (size_t)BB * 512 * NSP;      // 2*512*NSP
    float* bufX   = bufB + (size_t)BB * 512 * NSP;      // 2*128*NSP (x materialized)
    float* bufY   = bufX + (size_t)BB * 128 * NSP;      // 2*128*NSP (raw proj out)
    float* bufQKV = bufY + (size_t)BB * 128 * NSP;      // 2*384*NSP
    float* pl     = bufQKV + (size_t)BB * 384 * NSP;    // 16*6*NSP
    float* small  = pl + (size_t)16 * 6 * NSP;
    float* se_s   = small;                    // 1024
    float* st1    = small + 1024;             // 8 replicas x 512 (atomic, zeroed)
    float* st3    = small + 1024 + 4096;      // 8 replicas x 512 (atomic, zeroed)
    float* st4    = small + 1024 + 8192;      // 8 replicas x 512 (atomic, zeroed)
    float* st2    = small + 1024 + 12288;     // 512, plain write (post)
    short* wbf    = (short*)(small + 16384);  // 376832 bf16 weights
    float* po     = bufA;                     // attn partials 16*6*16*NSP

    // bf16 weight offsets (elements) — must match prep_kernel's table
    short* W_M1EW = wbf + 0;
    short* W_M1PW = wbf + 16384;
    short* W_M2EW = wbf + 49152;
    short* W_M2PW = wbf + 114688;
    short* W_QKV  = wbf + 180224;
    short* W_TPW  = wbf + 229376;
    short* W_MW1  = wbf + 245760;
    short* W_MW2  = wbf + 311296;

    dim3 blk(256);

    (void)hipMemsetAsync(st1, 0, 12288 * sizeof(float), stream);
    prep_kernel<<<(WTOT + 1023) / 1024, blk, 0, stream>>>(
        m1_ew, m1_pw, m2_ew, m2_pw, t_qkv, t_pw, t_mw1, t_mw2, wbf);

    // ---------------- MBConv1: 64 -> 256 -> 128 ----------------
    convm_kernel<64, 256><<<dim3(BB * 108, 4), blk, 0, stream>>>(
        x, W_M1EW, nullptr,
        nullptr, nullptr, nullptr, nullptr, nullptr, 0,
        nullptr, nullptr, nullptr, 0, 0,
        nullptr, nullptr, nullptr,
        nullptr, bufA, nullptr, 0);
    indw_kernel<<<BB * 256, blk, 0, stream>>>(bufA, m1_g1, m1_b1, m1_dw, m1_g2, m1_b2, bufB, se_s, 256);
    convm_kernel<256, 128><<<dim3(BB * 108, 2), blk, 0, stream>>>(   // proj + inline SE
        bufB, W_M1PW, nullptr,
        se_s, m1_sw1, m1_sb1, m1_sw2, m1_sb2, 64,
        nullptr, nullptr, nullptr, 0, 0,
        nullptr, nullptr, nullptr,
        nullptr, bufY, st1, 0);

    // ---------------- MBConv2: 128 -> 512 -> 128 (+res) ----------------
    convm_kernel<128, 512><<<dim3(BB * 108, 8), blk, 0, stream>>>(   // expand + IN-fold, side-write x1
        bufY, W_M2EW, nullptr,
        nullptr, nullptr, nullptr, nullptr, nullptr, 0,
        st1, m1_g3, m1_b3, 1, 8,
        nullptr, nullptr, bufX,
        nullptr, bufA, nullptr, 0);
    indw_kernel<<<BB * 512, blk, 0, stream>>>(bufA, m2_g1, m2_b1, m2_dw, m2_g2, m2_b2, bufB, se_s, 512);
    convm_kernel<512, 128><<<dim3(BB * 108, 2), blk, 0, stream>>>(   // proj + inline SE
        bufB, W_M2PW, nullptr,
        se_s, m2_sw1, m2_sb1, m2_sw2, m2_sb2, 128,
        nullptr, nullptr, nullptr, 0, 0,
        nullptr, nullptr, nullptr,
        nullptr, bufY, nullptr, 0);
    post_kernel<<<BB * 128, blk, 0, stream>>>(bufY, m2_g3, m2_b3, bufX, bufX, st2, 128);

    // ---------------- Transformer ----------------
    convm_kernel<128, 384><<<dim3(BB * 108, 6), blk, 0, stream>>>(   // qkv + gnorm1-fold
        bufX, W_QKV, nullptr,
        nullptr, nullptr, nullptr, nullptr, nullptr, 0,
        st2, t_n1g, t_n1b, 4, 1,
        nullptr, nullptr, nullptr,
        nullptr, bufQKV, nullptr, 0);
    attn_split_kernel<<<dim3(16, 27, 6), blk, 0, stream>>>(bufQKV, po, pl);
    convm_kernel<128, 128><<<dim3(BB * 108, 2), blk, 0, stream>>>(   // attn merge + proj + resid
        nullptr, W_TPW, t_pb,
        nullptr, nullptr, nullptr, nullptr, nullptr, 0,
        nullptr, nullptr, nullptr, 0, 0,
        po, pl, nullptr,
        bufX, bufX, st3, 0);
    convm_kernel<128, 512><<<dim3(BB * 108, 8), blk, 0, stream>>>(   // mlp1 + gnorm2-fold + GELU
        bufX, W_MW1, t_mb1,
        nullptr, nullptr, nullptr, nullptr, nullptr, 0,
        st3, t_n2g, t_n2b, 4, 8,
        nullptr, nullptr, nullptr,
        nullptr, bufA, nullptr, 2);
    convm_kernel<512, 128><<<dim3(BB * 108, 2), blk, 0, stream>>>(   // mlp2 + resid
        bufA, W_MW2, t_mb2,
        nullptr, nullptr, nullptr, nullptr, nullptr, 0,
        nullptr, nullptr, nullptr, 0, 0,
        nullptr, nullptr, nullptr,
        bufX, bufX, st4, 0);

    // ---------------- Shuffle attention ----------------
    sfinal_kernel<<<dim3(BB * 4, 27), dim3(64), 0, stream>>>(
        bufX, st4, s_cw1, s_cw2, s_gng, s_gnb, s_sw, out);
}

// Round 14
// 343.900 us; speedup vs baseline: 1.0249x; 1.0249x over previous
//
#include <hip/hip_runtime.h>
#include <cmath>

#define NSP 1728   // 12*12*12
#define BB  2      // batch
#define SS  12

typedef __attribute__((ext_vector_type(8))) short short8;
typedef __attribute__((ext_vector_type(4))) short short4v;
typedef __attribute__((ext_vector_type(4))) float floatx4;

__device__ __forceinline__ short f2bf(float f) {
    unsigned u = __float_as_uint(f);
    u += 0x7fff + ((u >> 16) & 1);
    return (short)(u >> 16);
}
__device__ __forceinline__ unsigned pack2bf(float a, float b) {
    unsigned ua = __float_as_uint(a); ua += 0x7fff + ((ua >> 16) & 1);
    unsigned ub = __float_as_uint(b); ub += 0x7fff + ((ub >> 16) & 1);
    return (ua >> 16) | (ub & 0xffff0000u);
}
__device__ __forceinline__ short8 ld8(const short* p) {
    short4v a = *(const short4v*)p;
    short4v b = *(const short4v*)(p + 4);
    return __builtin_shufflevector(a, b, 0, 1, 2, 3, 4, 5, 6, 7);
}
// raw hardware exp2 (1 inst; inputs here are O(±3), far from edge cases)
__device__ __forceinline__ float fexp2(float x) {
    float r;
    asm("v_exp_f32 %0, %1" : "=v"(r) : "v"(x));
    return r;
}

// ---------------- block-wide dual reduction (sum, sumsq) -------------------
__device__ __forceinline__ void block_reduce2(float& s, float& s2) {
    __shared__ float red[8][2];
    __syncthreads();
    #pragma unroll
    for (int o = 32; o; o >>= 1) {
        s  += __shfl_down(s,  o, 64);
        s2 += __shfl_down(s2, o, 64);
    }
    int lane = threadIdx.x & 63, w = threadIdx.x >> 6;
    if (lane == 0) { red[w][0] = s; red[w][1] = s2; }
    __syncthreads();
    int nw = (blockDim.x + 63) >> 6;
    if (threadIdx.x == 0) {
        float a = 0.f, b = 0.f;
        for (int i = 0; i < nw; i++) { a += red[i][0]; b += red[i][1]; }
        red[0][0] = a; red[0][1] = b;
    }
    __syncthreads();
    s = red[0][0]; s2 = red[0][1];
}

// ======= weight prep: fp32 -> bf16, all 8 conv weight matrices =============
// Blocks 0..5 additionally zero the 1536-float atomic-stats region (replaces
// the hipMemsetAsync node).
#define WTOT 376832
__global__ __launch_bounds__(256) void prep_kernel(
        const float* __restrict__ s0, const float* __restrict__ s1,
        const float* __restrict__ s2, const float* __restrict__ s3,
        const float* __restrict__ s4, const float* __restrict__ s5,
        const float* __restrict__ s6, const float* __restrict__ s7,
        short* __restrict__ dst, float* __restrict__ stz) {
    if (blockIdx.x < 6) stz[blockIdx.x * 256 + threadIdx.x] = 0.f;
    const int offs[9] = {0, 16384, 49152, 114688, 180224, 229376, 245760, 311296, WTOT};
    const float* srcs[8] = {s0, s1, s2, s3, s4, s5, s6, s7};
    int e = blockIdx.x * 1024 + threadIdx.x * 4;
    #pragma unroll
    for (int k = 0; k < 4; k++) {
        int idx = e + k;
        if (idx >= WTOT) return;
        int seg = 0;
        while (idx >= offs[seg + 1]) seg++;
        dst[idx] = f2bf(srcs[seg][idx - offs[seg]]);
    }
}

// ======= MFMA 1x1 conv =====================================================
// C^T[n][co] = X'^T[n][ci] x W[co][ci]:  M = n (16/block), N = co, K = ci.
// grid (BB*108 n-tiles, COUT/64 co-tiles); 4 waves, each owns 16 cos.
// Staging variants: normal (in + fold/SE scale-shift) or attention-merge
// (po/pl partials -> merged O), fp32 math pre-bf16-round.
template<int CIN, int COUT>
__global__ __launch_bounds__(256) void convm_kernel(
        const float* __restrict__ in, const short* __restrict__ wb,
        const float* __restrict__ biasc,
        const float* __restrict__ se_s,
        const float* __restrict__ sw1, const float* __restrict__ sb1,
        const float* __restrict__ sw2, const float* __restrict__ sb2, int seR,
        const float* __restrict__ fstats, const float* __restrict__ fg,
        const float* __restrict__ fb, int fgs,
        const float* __restrict__ po, const float* __restrict__ pl,
        float* __restrict__ xout,
        const float* resid, float* out, float* stats_out, int act) {
    constexpr int XP = CIN + 8;          // bf16 row pitch (16B-multiple rows)
    __shared__ float sc[CIN];
    __shared__ float sh[CIN];
    __shared__ float hid[128];
    __shared__ __align__(16) short xa[16 * XP];
    int flat = blockIdx.x;
    int b = flat / 108, mt = flat % 108;
    int n0 = mt * 16;
    int tid = threadIdx.x;

    if (po) {
        // ---- attention-merge staging: X = (sum_js po) / l, ci = h*16+d ----
        if (tid < 128) {
            int hh = tid >> 4, j = tid & 15;
            float l = 0.f;
            #pragma unroll
            for (int js = 0; js < 6; js++)
                l += pl[(size_t)((b * 8 + hh) * 6 + js) * NSP + n0 + j];
            hid[tid] = 1.f / l;
        }
        __syncthreads();
        #pragma unroll
        for (int i = 0; i < CIN / 64; i++) {
            int e = tid + i * 256;
            int ci = e >> 2;
            int jj = (e & 3) * 4;
            int hh = ci >> 4, d = ci & 15;
            float4 acc = {0.f, 0.f, 0.f, 0.f};
            #pragma unroll
            for (int js = 0; js < 6; js++) {
                float4 pv = *(const float4*)(po +
                    ((size_t)((b * 8 + hh) * 6 + js) * 16 + d) * NSP + n0 + jj);
                acc.x += pv.x; acc.y += pv.y; acc.z += pv.z; acc.w += pv.w;
            }
            float4 li = *(const float4*)(hid + hh * 16 + jj);
            xa[(jj + 0) * XP + ci] = f2bf(acc.x * li.x);
            xa[(jj + 1) * XP + ci] = f2bf(acc.y * li.y);
            xa[(jj + 2) * XP + ci] = f2bf(acc.z * li.z);
            xa[(jj + 3) * XP + ci] = f2bf(acc.w * li.w);
        }
        __syncthreads();
    } else {
    // ---- preamble: per-ci scale/shift ----
    if (sw1) {
        for (int c = tid; c < CIN; c += 256) { sc[c] = se_s[b * CIN + c]; sh[c] = 0.f; }
        __syncthreads();
        for (int r = tid; r < seR; r += 256) {
            const float* wr = sw1 + (size_t)r * CIN;
            float h0 = sb1[r], h1 = 0.f, h2 = 0.f, h3 = 0.f;
            for (int c = 0; c < CIN; c += 4) {
                h0 = fmaf(wr[c],     sc[c],     h0);
                h1 = fmaf(wr[c + 1], sc[c + 1], h1);
                h2 = fmaf(wr[c + 2], sc[c + 2], h2);
                h3 = fmaf(wr[c + 3], sc[c + 3], h3);
            }
            float hv = (h0 + h1) + (h2 + h3);
            hid[r] = hv / (1.f + __expf(-hv));
        }
        __syncthreads();
        for (int ci = tid; ci < CIN; ci += 256) {
            const float* wr = sw2 + (size_t)ci * seR;
            float g0 = sb2[ci], g1 = 0.f, g2 = 0.f, g3 = 0.f;
            for (int r = 0; r < seR; r += 4) {
                g0 = fmaf(wr[r],     hid[r],     g0);
                g1 = fmaf(wr[r + 1], hid[r + 1], g1);
                g2 = fmaf(wr[r + 2], hid[r + 2], g2);
                g3 = fmaf(wr[r + 3], hid[r + 3], g3);
            }
            float gv = (g0 + g1) + (g2 + g3);
            sc[ci] = 1.f / (1.f + __expf(-gv));
        }
    } else if (fstats) {
        for (int c = tid; c < CIN; c += 256) {
            int g0 = c / fgs;
            float S = 0.f, S2 = 0.f;
            for (int k = 0; k < fgs; k++) {
                S  += fstats[(b * CIN + g0 * fgs + k) * 2];
                S2 += fstats[(b * CIN + g0 * fgs + k) * 2 + 1];
            }
            float N = fgs * (float)NSP;
            float mean = S / N, var = S2 / N - mean * mean;
            float s = rsqrtf(var + 1e-5f) * fg[c];
            sc[c] = s;
            sh[c] = fb[c] - mean * s;
        }
    } else {
        for (int c = tid; c < CIN; c += 256) { sc[c] = 1.f; sh[c] = 0.f; }
    }
    __syncthreads();

    // ---- stage X' tile [n=16][ci] bf16 (fp32 fold applied pre-round) ----
    bool dosw = (xout != nullptr) && (blockIdx.y == 0);
    #pragma unroll
    for (int i = 0; i < CIN / 64; i++) {
        int e = tid + i * 256;           // e in [0, 4*CIN)
        int ci = e >> 2;
        int jj = (e & 3) * 4;
        size_t gi = ((size_t)b * CIN + ci) * NSP + n0 + jj;
        float4 v4 = *(const float4*)(in + gi);
        float s_ = sc[ci], h_ = sh[ci];
        float v0 = fmaf(v4.x, s_, h_), v1 = fmaf(v4.y, s_, h_);
        float v2 = fmaf(v4.z, s_, h_), v3 = fmaf(v4.w, s_, h_);
        if (dosw) {
            float4 o; o.x = v0; o.y = v1; o.z = v2; o.w = v3;
            *(float4*)(xout + gi) = o;
        }
        xa[(jj + 0) * XP + ci] = f2bf(v0);
        xa[(jj + 1) * XP + ci] = f2bf(v1);
        xa[(jj + 2) * XP + ci] = f2bf(v2);
        xa[(jj + 3) * XP + ci] = f2bf(v3);
    }
    __syncthreads();
    }

    // ---- compute: no further barriers ----
    int lane = tid & 63, wv = tid >> 6;
    int col = lane & 15, quad = lane >> 4;
    short8 afr[CIN / 32];
    #pragma unroll
    for (int kc = 0; kc < CIN / 32; kc++)
        afr[kc] = ld8(xa + col * XP + kc * 32 + quad * 8);

    int cobase = blockIdx.y * 64 + wv * 16;
    int co = cobase + col;
    const short* wrow = wb + (size_t)co * CIN;
    floatx4 acc = {0.f, 0.f, 0.f, 0.f};
    #pragma unroll
    for (int kc = 0; kc < CIN / 32; kc++) {
        short8 bw = ld8(wrow + kc * 32 + quad * 8);
        acc = __builtin_amdgcn_mfma_f32_16x16x32_bf16(afr[kc], bw, acc, 0, 0, 0);
    }
    float bv = biasc ? biasc[co] : 0.f;
    float r0 = acc[0] + bv, r1 = acc[1] + bv, r2 = acc[2] + bv, r3 = acc[3] + bv;
    if (act == 2) {
        r0 = 0.5f * r0 * (1.f + erff(r0 * 0.70710678118654752f));
        r1 = 0.5f * r1 * (1.f + erff(r1 * 0.70710678118654752f));
        r2 = 0.5f * r2 * (1.f + erff(r2 * 0.70710678118654752f));
        r3 = 0.5f * r3 * (1.f + erff(r3 * 0.70710678118654752f));
    }
    size_t oi = ((size_t)b * COUT + co) * NSP + n0 + quad * 4;
    if (resid) {
        float4 rv = *(const float4*)(resid + oi);
        r0 += rv.x; r1 += rv.y; r2 += rv.z; r3 += rv.w;
    }
    float4 ov; ov.x = r0; ov.y = r1; ov.z = r2; ov.w = r3;
    *(float4*)(out + oi) = ov;
    if (stats_out) {
        float s  = (r0 + r1) + (r2 + r3);
        float s2 = (r0 * r0 + r1 * r1) + (r2 * r2 + r3 * r3);
        s  += __shfl_xor(s,  16, 64);
        s  += __shfl_xor(s,  32, 64);
        s2 += __shfl_xor(s2, 16, 64);
        s2 += __shfl_xor(s2, 32, 64);
        if (lane < 16) {
            atomicAdd(&stats_out[(b * COUT + cobase + lane) * 2],     s);
            atomicAdd(&stats_out[(b * COUT + cobase + lane) * 2 + 1], s2);
        }
    }
}

// ======= post: out = IN(p0) + resid, emits raw stats of out ================
__global__ __launch_bounds__(256) void post_kernel(
        const float* __restrict__ p0,
        const float* __restrict__ ng, const float* __restrict__ nb,
        const float* resid, float* out, float* __restrict__ stats_out, int C) {
    int bc = blockIdx.x;
    int c  = bc % C;
    const float* a = p0 + (size_t)bc * NSP;
    float r[7];
    float s = 0.f, s2 = 0.f;
    #pragma unroll
    for (int i = 0; i < 7; i++) {
        int n = threadIdx.x + i * 256;
        if (n < NSP) { r[i] = a[n]; s += r[i]; s2 += r[i] * r[i]; }
        else r[i] = 0.f;
    }
    block_reduce2(s, s2);
    float mean = s / NSP;
    float var = s2 / NSP - mean * mean;
    float rstd = rsqrtf(var + 1e-5f);
    float gc = ng[c], bc2 = nb[c];
    float os = 0.f, os2 = 0.f;
    #pragma unroll
    for (int i = 0; i < 7; i++) {
        int n = threadIdx.x + i * 256;
        if (n < NSP) {
            float v = (r[i] - mean) * rstd * gc + bc2;
            size_t oi = (size_t)bc * NSP + n;
            if (resid) v += resid[oi];
            out[oi] = v;
            os += v; os2 += v * v;
        }
    }
    if (stats_out) {
        block_reduce2(os, os2);
        if (threadIdx.x == 0) {
            stats_out[bc * 2]     = os;
            stats_out[bc * 2 + 1] = os2;
        }
    }
}

// ======= IN+SiLU + depthwise 3x3x3 (halo LDS) + IN+SiLU + SE-squeeze =======
__global__ __launch_bounds__(256) void indw_kernel(
        const float* __restrict__ in,
        const float* __restrict__ g1, const float* __restrict__ b1,
        const float* __restrict__ dw,
        const float* __restrict__ g2, const float* __restrict__ b2,
        float* __restrict__ out, float* __restrict__ se_s, int C) {
    int bc = blockIdx.x;
    int c  = bc % C;
    __shared__ float tile[14 * 14 * 14];   // zero-padded halo volume
    __shared__ float wsh[27];
    const float* ip = in + (size_t)bc * NSP;
    float r[7];
    float s = 0.f, s2 = 0.f;
    for (int i = threadIdx.x; i < 2744; i += 256) tile[i] = 0.f;
    #pragma unroll
    for (int i = 0; i < 7; i++) {
        int n = threadIdx.x + i * 256;
        if (n < NSP) { r[i] = ip[n]; s += r[i]; s2 += r[i] * r[i]; }
        else r[i] = 0.f;
    }
    if (threadIdx.x < 27) wsh[threadIdx.x] = dw[(size_t)c * 27 + threadIdx.x];
    block_reduce2(s, s2);
    float mean = s / NSP, var = s2 / NSP - (s / NSP) * (s / NSP);
    float rstd = rsqrtf(var + 1e-5f);
    float gc = g1[c], bc1 = b1[c];
    #pragma unroll
    for (int i = 0; i < 7; i++) {
        int n = threadIdx.x + i * 256;
        if (n < NSP) {
            int z = n / 144, y = (n / 12) % 12, x = n % 12;
            float v = (r[i] - mean) * rstd * gc + bc1;
            tile[((z + 1) * 14 + y + 1) * 14 + x + 1] = v / (1.f + __expf(-v));
        }
    }
    __syncthreads();
    float d[7];
    #pragma unroll
    for (int i = 0; i < 7; i++) {
        int n = threadIdx.x + i * 256;
        d[i] = 0.f;
        if (n < NSP) {
            int z = n / 144, y = (n / 12) % 12, x = n % 12;
            const float* ctr = tile + ((z + 1) * 14 + y + 1) * 14 + x + 1;
            float acc = 0.f;
            #pragma unroll
            for (int dz = 0; dz < 3; dz++)
                #pragma unroll
                for (int dy = 0; dy < 3; dy++)
                    #pragma unroll
                    for (int dx = 0; dx < 3; dx++)
                        acc = fmaf(wsh[dz * 9 + dy * 3 + dx],
                                   ctr[(dz - 1) * 196 + (dy - 1) * 14 + (dx - 1)], acc);
            d[i] = acc;
        }
    }
    s = 0.f; s2 = 0.f;
    #pragma unroll
    for (int i = 0; i < 7; i++) {
        int n = threadIdx.x + i * 256;
        if (n < NSP) { s += d[i]; s2 += d[i] * d[i]; }
    }
    block_reduce2(s, s2);
    mean = s / NSP; var = s2 / NSP - mean * mean;
    rstd = rsqrtf(var + 1e-5f);
    float gc2 = g2[c], bc2 = b2[c];
    float ssum = 0.f;
    float* op = out + (size_t)bc * NSP;
    #pragma unroll
    for (int i = 0; i < 7; i++) {
        int n = threadIdx.x + i * 256;
        if (n < NSP) {
            float v = (d[i] - mean) * rstd * gc2 + bc2;
            v = v / (1.f + __expf(-v));
            op[n] = v;
            ssum += v;
        }
    }
    float dummy = 0.f;
    block_reduce2(ssum, dummy);
    if (threadIdx.x == 0) se_s[bc] = ssum / NSP;
}

// ======= MFMA flash attention, j-split 6, S^T formulation ==================
#define AKT 20
#define AVT 296
#define APT 36
#define JCH 288
__global__ __launch_bounds__(256) void attn_split_kernel(const float* __restrict__ qkv,
                                                         float* __restrict__ po,
                                                         float* __restrict__ pl) {
    __shared__ __align__(16) short kt[JCH * AKT];   // [j][d]
    __shared__ __align__(16) short vt[16 * AVT];    // [d][j]
    __shared__ __align__(16) short pt[4][16 * APT]; // per wave [q][j]
    int bh = blockIdx.x;
    int b = bh >> 3, h = bh & 7;
    int js = blockIdx.z;
    int j0 = js * JCH;
    const float* base = qkv + (size_t)b * 384 * NSP;
    const float* qp = base + (size_t)(h * 16) * NSP;
    const float* kp = base + (size_t)(128 + h * 16) * NSP;
    const float* vp = base + (size_t)(256 + h * 16) * NSP;
    for (int t = threadIdx.x; t < 16 * 144; t += 256) {
        int d = t / 144, j = (t - d * 144) * 2;
        float2 kv2 = *(const float2*)(kp + (size_t)d * NSP + j0 + j);
        float2 vv2 = *(const float2*)(vp + (size_t)d * NSP + j0 + j);
        kt[j * AKT + d]       = f2bf(kv2.x);
        kt[(j + 1) * AKT + d] = f2bf(kv2.y);
        *(unsigned*)(vt + d * AVT + j) = pack2bf(vv2.x, vv2.y);
    }
    int wave = threadIdx.x >> 6, lane = threadIdx.x & 63;
    int m = lane & 15, quad = lane >> 4;
    int q0 = (blockIdx.y * 4 + wave) * 16;
    short* ptw = pt[wave];
    short8 qa;
    #pragma unroll
    for (int i = 0; i < 8; i++) qa[i] = 0;
    if (quad < 2) {
        #pragma unroll
        for (int i = 0; i < 8; i++) {
            int d = quad * 8 + i;
            qa[i] = f2bf(qp[(size_t)d * NSP + q0 + m] * 0.36067376022224085f);
        }
    }
    __syncthreads();
    floatx4 o = {0.f, 0.f, 0.f, 0.f};
    float ls = 0.f;
    for (int s = 0; s < 9; s++) {
        int jl = s * 32;
        short8 ak0, ak1;
        #pragma unroll
        for (int i = 0; i < 8; i++) { ak0[i] = 0; ak1[i] = 0; }
        if (quad < 2) {
            ak0 = ld8(kt + (jl + m) * AKT + quad * 8);
            ak1 = ld8(kt + (jl + 16 + m) * AKT + quad * 8);
        }
        floatx4 s0 = {0.f, 0.f, 0.f, 0.f}, s1 = {0.f, 0.f, 0.f, 0.f};
        s0 = __builtin_amdgcn_mfma_f32_16x16x32_bf16(ak0, qa, s0, 0, 0, 0);
        s1 = __builtin_amdgcn_mfma_f32_16x16x32_bf16(ak1, qa, s1, 0, 0, 0);
        float p0r0 = fexp2(s0[0]), p0r1 = fexp2(s0[1]), p0r2 = fexp2(s0[2]), p0r3 = fexp2(s0[3]);
        float p1r0 = fexp2(s1[0]), p1r1 = fexp2(s1[1]), p1r2 = fexp2(s1[2]), p1r3 = fexp2(s1[3]);
        ls += (p0r0 + p0r1) + (p0r2 + p0r3) + (p1r0 + p1r1) + (p1r2 + p1r3);
        uint2 w0, w1;
        w0.x = pack2bf(p0r0, p0r1); w0.y = pack2bf(p0r2, p0r3);
        w1.x = pack2bf(p1r0, p1r1); w1.y = pack2bf(p1r2, p1r3);
        *(uint2*)(ptw + m * APT + quad * 4)      = w0;
        *(uint2*)(ptw + m * APT + 16 + quad * 4) = w1;
        short8 av = ld8(vt + m * AVT + jl + quad * 8);
        short8 pb = ld8(ptw + m * APT + quad * 8);
        o = __builtin_amdgcn_mfma_f32_16x16x32_bf16(av, pb, o, 0, 0, 0);
    }
    ls += __shfl_xor(ls, 16, 64);
    ls += __shfl_xor(ls, 32, 64);
    size_t pbase = ((size_t)(bh * 6 + js) * 16) * NSP;
    #pragma unroll
    for (int r = 0; r < 4; r++)
        po[pbase + (size_t)(quad * 4 + r) * NSP + q0 + m] = o[r];
    if (quad == 0) pl[(size_t)(bh * 6 + js) * NSP + q0 + m] = ls;
}

// ======= shuffle attn final: inline gates + gnstats + gating + shuffle =====
__global__ void sfinal_kernel(const float* __restrict__ X,
                              const float* __restrict__ st,
                              const float* __restrict__ cw1,
                              const float* __restrict__ cw2,
                              const float* __restrict__ gng,
                              const float* __restrict__ gnb,
                              const float* __restrict__ sw,
                              float* __restrict__ out) {
    int bg = blockIdx.x;
    int b = bg >> 2, g = bg & 3;
    __shared__ float swl[256];
    for (int i = threadIdx.x; i < 256; i += 64) swl[i] = sw[i];
    __syncthreads();
    float pooled[16];
    #pragma unroll
    for (int j = 0; j < 16; j++)
        pooled[j] = st[(b * 128 + g * 32 + j) * 2] * (1.f / NSP);
    float hid[4];
    #pragma unroll
    for (int r = 0; r < 4; r++) {
        float a = 0.f;
        #pragma unroll
        for (int j = 0; j < 16; j++) a = fmaf(cw1[r * 16 + j], pooled[j], a);
        hid[r] = a / (1.f + __expf(-a));
    }
    float gate[16];
    #pragma unroll
    for (int j = 0; j < 16; j++) {
        float a = 0.f;
        #pragma unroll
        for (int r = 0; r < 4; r++) a = fmaf(cw2[j * 4 + r], hid[r], a);
        gate[j] = 1.f / (1.f + __expf(-a));
    }
    float gmean[2], grstd[2];
    #pragma unroll
    for (int t = 0; t < 2; t++) {
        float S = 0.f, S2 = 0.f;
        #pragma unroll
        for (int k = 0; k < 8; k++) {
            int c = g * 32 + 16 + t * 8 + k;
            S  += st[(b * 128 + c) * 2];
            S2 += st[(b * 128 + c) * 2 + 1];
        }
        float N = 8.f * NSP;
        gmean[t] = S / N;
        grstd[t] = rsqrtf(S2 / N - gmean[t] * gmean[t] + 1e-5f);
    }
    int n = blockIdx.y * 64 + threadIdx.x;
    const float* xb = X + (size_t)b * 128 * NSP;
    #pragma unroll
    for (int j = 0; j < 16; j++) {
        float v = xb[(size_t)(g * 32 + j) * NSP + n] * gate[j];
        int k = g * 16 + j;
        int cp = (k % 32) * 4 + (k / 32);
        out[((size_t)b * 128 + cp) * NSP + n] = v;
    }
    float sgn[16];
    #pragma unroll
    for (int j = 0; j < 16; j++) {
        int grp = j >> 3;
        float xv = xb[(size_t)(g * 32 + 16 + j) * NSP + n];
        sgn[j] = (xv - gmean[grp]) * grstd[grp] * gng[j] + gnb[j];
    }
    #pragma unroll
    for (int j = 0; j < 16; j++) {
        float a = 0.f;
        #pragma unroll
        for (int jp = 0; jp < 16; jp++) a = fmaf(swl[j * 16 + jp], sgn[jp], a);
        float v = (1.f / (1.f + __expf(-a))) * xb[(size_t)(g * 32 + 16 + j) * NSP + n];
        int k = 64 + g * 16 + j;
        int cp = (k % 32) * 4 + (k / 32);
        out[((size_t)b * 128 + cp) * NSP + n] = v;
    }
}

// ===========================================================================
extern "C" void kernel_launch(void* const* d_in, const int* in_sizes, int n_in,
                              void* d_out, int out_size, void* d_ws, size_t ws_size,
                              hipStream_t stream) {
    const float* x     = (const float*)d_in[0];
    const float* m1_ew = (const float*)d_in[1];
    const float* m1_g1 = (const float*)d_in[2];
    const float* m1_b1 = (const float*)d_in[3];
    const float* m1_dw = (const float*)d_in[4];
    const float* m1_g2 = (const float*)d_in[5];
    const float* m1_b2 = (const float*)d_in[6];
    const float* m1_sw1= (const float*)d_in[7];
    const float* m1_sb1= (const float*)d_in[8];
    const float* m1_sw2= (const float*)d_in[9];
    const float* m1_sb2= (const float*)d_in[10];
    const float* m1_pw = (const float*)d_in[11];
    const float* m1_g3 = (const float*)d_in[12];
    const float* m1_b3 = (const float*)d_in[13];
    const float* m2_ew = (const float*)d_in[14];
    const float* m2_g1 = (const float*)d_in[15];
    const float* m2_b1 = (const float*)d_in[16];
    const float* m2_dw = (const float*)d_in[17];
    const float* m2_g2 = (const float*)d_in[18];
    const float* m2_b2 = (const float*)d_in[19];
    const float* m2_sw1= (const float*)d_in[20];
    const float* m2_sb1= (const float*)d_in[21];
    const float* m2_sw2= (const float*)d_in[22];
    const float* m2_sb2= (const float*)d_in[23];
    const float* m2_pw = (const float*)d_in[24];
    const float* m2_g3 = (const float*)d_in[25];
    const float* m2_b3 = (const float*)d_in[26];
    const float* t_n1g = (const float*)d_in[27];
    const float* t_n1b = (const float*)d_in[28];
    const float* t_qkv = (const float*)d_in[29];
    const float* t_pw  = (const float*)d_in[30];
    const float* t_pb  = (const float*)d_in[31];
    const float* t_n2g = (const float*)d_in[32];
    const float* t_n2b = (const float*)d_in[33];
    const float* t_mw1 = (const float*)d_in[34];
    const float* t_mb1 = (const float*)d_in[35];
    const float* t_mw2 = (const float*)d_in[36];
    const float* t_mb2 = (const float*)d_in[37];
    const float* s_cw1 = (const float*)d_in[38];
    const float* s_cw2 = (const float*)d_in[39];
    const float* s_gng = (const float*)d_in[40];
    const float* s_gnb = (const float*)d_in[41];
    const float* s_sw  = (const float*)d_in[42];

    float* out = (float*)d_out;

    float* ws = (float*)d_ws;
    float* bufA   = ws;                                 // 2*512*NSP (also attn po)
    float* bufB   = bufA + (size_t)BB * 512 * NSP;      // 2*512*NSP
    float* bufX   = bufB + (size_t)BB * 512 * NSP;      // 2*128*NSP (x materialized)
    float* bufY   = bufX + (size_t)BB * 128 * NSP;      // 2*128*NSP (raw proj out)
    float* bufQKV = bufY + (size_t)BB * 128 * NSP;      // 2*384*NSP
    float* pl     = bufQKV + (size_t)BB * 384 * NSP;    // 16*6*NSP
    float* small  = pl + (size_t)16 * 6 * NSP;
    float* se_s   = small;            // 1024
    float* st1    = small + 1024;     // 512, m1proj raw stats (atomic, zeroed by prep)
    float* st3    = small + 1536;     // 512, attn-proj stats (atomic, zeroed by prep)
    float* st4    = small + 2048;     // 512, mlp2 stats (atomic, zeroed by prep)
    float* st2    = small + 2560;     // 512, x2 stats (plain write)
    short* wbf    = (short*)(small + 8192);   // 376832 bf16 weights
    float* po     = bufA;             // attn partials 16*6*16*NSP

    // bf16 weight offsets (elements) — must match prep_kernel's table
    short* W_M1EW = wbf + 0;
    short* W_M1PW = wbf + 16384;
    short* W_M2EW = wbf + 49152;
    short* W_M2PW = wbf + 114688;
    short* W_QKV  = wbf + 180224;
    short* W_TPW  = wbf + 229376;
    short* W_MW1  = wbf + 245760;
    short* W_MW2  = wbf + 311296;

    dim3 blk(256);

    prep_kernel<<<(WTOT + 1023) / 1024, blk, 0, stream>>>(
        m1_ew, m1_pw, m2_ew, m2_pw, t_qkv, t_pw, t_mw1, t_mw2, wbf, st1);

    // ---------------- MBConv1: 64 -> 256 -> 128 ----------------
    convm_kernel<64, 256><<<dim3(BB * 108, 4), blk, 0, stream>>>(
        x, W_M1EW, nullptr,
        nullptr, nullptr, nullptr, nullptr, nullptr, 0,
        nullptr, nullptr, nullptr, 0,
        nullptr, nullptr, nullptr,
        nullptr, bufA, nullptr, 0);
    indw_kernel<<<BB * 256, blk, 0, stream>>>(bufA, m1_g1, m1_b1, m1_dw, m1_g2, m1_b2, bufB, se_s, 256);
    convm_kernel<256, 128><<<dim3(BB * 108, 2), blk, 0, stream>>>(   // proj + inline SE
        bufB, W_M1PW, nullptr,
        se_s, m1_sw1, m1_sb1, m1_sw2, m1_sb2, 64,
        nullptr, nullptr, nullptr, 0,
        nullptr, nullptr, nullptr,
        nullptr, bufY, st1, 0);

    // ---------------- MBConv2: 128 -> 512 -> 128 (+res) ----------------
    convm_kernel<128, 512><<<dim3(BB * 108, 8), blk, 0, stream>>>(   // expand + IN-fold, side-write x1
        bufY, W_M2EW, nullptr,
        nullptr, nullptr, nullptr, nullptr, nullptr, 0,
        st1, m1_g3, m1_b3, 1,
        nullptr, nullptr, bufX,
        nullptr, bufA, nullptr, 0);
    indw_kernel<<<BB * 512, blk, 0, stream>>>(bufA, m2_g1, m2_b1, m2_dw, m2_g2, m2_b2, bufB, se_s, 512);
    convm_kernel<512, 128><<<dim3(BB * 108, 2), blk, 0, stream>>>(   // proj + inline SE
        bufB, W_M2PW, nullptr,
        se_s, m2_sw1, m2_sb1, m2_sw2, m2_sb2, 128,
        nullptr, nullptr, nullptr, 0,
        nullptr, nullptr, nullptr,
        nullptr, bufY, nullptr, 0);
    post_kernel<<<BB * 128, blk, 0, stream>>>(bufY, m2_g3, m2_b3, bufX, bufX, st2, 128);

    // ---------------- Transformer ----------------
    convm_kernel<128, 384><<<dim3(BB * 108, 6), blk, 0, stream>>>(   // qkv + gnorm1-fold
        bufX, W_QKV, nullptr,
        nullptr, nullptr, nullptr, nullptr, nullptr, 0,
        st2, t_n1g, t_n1b, 4,
        nullptr, nullptr, nullptr,
        nullptr, bufQKV, nullptr, 0);
    attn_split_kernel<<<dim3(16, 27, 6), blk, 0, stream>>>(bufQKV, po, pl);
    convm_kernel<128, 128><<<dim3(BB * 108, 2), blk, 0, stream>>>(   // attn merge + proj + resid
        nullptr, W_TPW, t_pb,
        nullptr, nullptr, nullptr, nullptr, nullptr, 0,
        nullptr, nullptr, nullptr, 0,
        po, pl, nullptr,
        bufX, bufX, st3, 0);
    convm_kernel<128, 512><<<dim3(BB * 108, 8), blk, 0, stream>>>(   // mlp1 + gnorm2-fold + GELU
        bufX, W_MW1, t_mb1,
        nullptr, nullptr, nullptr, nullptr, nullptr, 0,
        st3, t_n2g, t_n2b, 4,
        nullptr, nullptr, nullptr,
        nullptr, bufA, nullptr, 2);
    convm_kernel<512, 128><<<dim3(BB * 108, 2), blk, 0, stream>>>(   // mlp2 + resid
        bufA, W_MW2, t_mb2,
        nullptr, nullptr, nullptr, nullptr, nullptr, 0,
        nullptr, nullptr, nullptr, 0,
        nullptr, nullptr, nullptr,
        bufX, bufX, st4, 0);

    // ---------------- Shuffle attention ----------------
    sfinal_kernel<<<dim3(BB * 4, 27), dim3(64), 0, stream>>>(
        bufX, st4, s_cw1, s_cw2, s_gng, s_gnb, s_sw, out);
}